// Round 11
// baseline (473.409 us; speedup 1.0000x reference)
//
#include <hip/hip_runtime.h>
#include <hip/hip_bf16.h>

#define HD 64

typedef unsigned short u16;

__device__ __forceinline__ float lrelu(float x) { return x > 0.f ? x : 0.2f * x; }
__device__ __forceinline__ int clampi(int v, int maxv) {
    return v < 0 ? 0 : (v >= maxv ? maxv - 1 : v);
}

// ---------------- init (zero deg/cursor/pooled) + node embedding + Ws/Wd precompute -------
// wsd[l][idx][d], idx = h*2+sel (sel 0=src,1=dst):
//   wsd = sum_c W_l[d][h*64+c] * att_{src|dst}[l][h][c]
// so a_s[n,h] = sum_d h[n,d]*wsd[l][h*2+0][d]  (linearity of the attention dot).
__global__ void k_init(const float* __restrict__ x, const float* __restrict__ W,
                       const float* __restrict__ b, float* __restrict__ h,
                       const float* __restrict__ lin_W, const float* __restrict__ att_src,
                       const float* __restrict__ att_dst, float* __restrict__ wsd,
                       int* deg, int* cursor, float* pooled, int N, int B) {
    int i = blockIdx.x * blockDim.x + threadIdx.x;
    if (i < N) { deg[i] = 0; cursor[i] = 0; }
    if (i < B * HD) pooled[i] = 0.f;
    if (i < 3 * 512) {
        int l = i >> 9, r = i & 511;
        int idx = r >> 6, d = r & 63;
        int hh = idx >> 1, sel = idx & 1;
        const float* att = (sel ? att_dst : att_src) + l * 256 + hh * 64;
        const float* Wrow = lin_W + (size_t)l * HD * 256 + d * 256 + hh * 64;
        float acc = 0.f;
        for (int c = 0; c < 64; c++) acc = fmaf(Wrow[c], att[c], acc);
        wsd[(l << 9) + (idx << 6) + d] = acc;
    }
    if (i < N * HD) {
        int n = i >> 6, c = i & 63;
        float acc = b[c];
        acc = fmaf(x[n * 3 + 0], W[0 * HD + c], acc);
        acc = fmaf(x[n * 3 + 1], W[1 * HD + c], acc);
        acc = fmaf(x[n * 3 + 2], W[2 * HD + c], acc);
        h[i] = fmaxf(acc, 0.f);
    }
}

// ---------------- a_s/a_d from current h (launched per layer; cheap, proven) ----------
__global__ void k_att(const float* __restrict__ h, const float* __restrict__ wsdl,
                      float* __restrict__ a_s, float* __restrict__ a_d, int N) {
    int i = blockIdx.x * blockDim.x + threadIdx.x;
    if (i >= N * 8) return;
    int n = i >> 3, idx = i & 7;
    const float* hr = h + (size_t)n * HD;
    const float* wp = wsdl + (idx << 6);
    float a = 0.f;
    for (int d = 0; d < HD; d += 4) {
        float4 hv = *(const float4*)(hr + d);
        float4 wv = *(const float4*)(wp + d);
        a = fmaf(hv.x, wv.x, a); a = fmaf(hv.y, wv.y, a);
        a = fmaf(hv.z, wv.z, a); a = fmaf(hv.w, wv.w, a);
    }
    int hd = idx >> 1, sel = idx & 1;
    if (sel) a_d[n * 4 + hd] = a;
    else     a_s[n * 4 + hd] = a;
}

// ---------------- degree histogram over dst ----------------
__global__ void k_deg(const int* __restrict__ dst, int* __restrict__ deg, int E, int N) {
    int e = blockIdx.x * blockDim.x + threadIdx.x;
    if (e < E) atomicAdd(&deg[clampi(dst[e], N)], 1);
}

// ---------------- hierarchical scan (2 kernels) ----------------
__global__ void k_scan1(const int* __restrict__ deg, int* __restrict__ tmp,
                        int* __restrict__ bsum, int N) {
    __shared__ int s[256];
    int tid = threadIdx.x;
    int i = blockIdx.x * 256 + tid;
    int v = (i < N) ? deg[i] : 0;
    s[tid] = v;
    __syncthreads();
    for (int off = 1; off < 256; off <<= 1) {
        int t = (tid >= off) ? s[tid - off] : 0;
        __syncthreads();
        s[tid] += t;
        __syncthreads();
    }
    if (i < N) tmp[i] = s[tid];
    if (tid == 255) bsum[blockIdx.x] = s[255];
}
__global__ void k_scan23(const int* __restrict__ tmp, const int* __restrict__ bsum,
                         int* __restrict__ row_ptr, int N) {
    __shared__ int s_off;
    int t = threadIdx.x;
    if (t < 64) {
        int cnt = blockIdx.x;
        int v = 0;
        for (int base = 0; base < cnt; base += 64)
            if (base + t < cnt) v += bsum[base + t];
        #pragma unroll
        for (int o = 32; o > 0; o >>= 1) v += __shfl_xor(v, o);
        if (t == 0) s_off = v;
    }
    __syncthreads();
    int i = blockIdx.x * 256 + t;
    if (i == 0) row_ptr[0] = 0;
    if (i < N) row_ptr[i + 1] = tmp[i] + s_off;
}

// ---------------- CSR scatter; packed {src, eid} int2 per slot ----------------
__global__ void k_csr(const int* __restrict__ src, const int* __restrict__ dst,
                      const int* __restrict__ row_ptr, int* __restrict__ cursor,
                      int2* __restrict__ csr_se, int E, int N) {
    int e = blockIdx.x * blockDim.x + threadIdx.x;
    if (e >= E) return;
    int d = clampi(dst[e], N);
    int pos = row_ptr[d] + atomicAdd(&cursor[d], 1);
    if (pos < E) csr_se[pos] = make_int2(clampi(src[e], N), e);
}

// ---------------- ONCE: a_ed for all 3 layers x 4 heads, CSR order ----------------
// planar output: aed[l][(E+N)][4]
__global__ __launch_bounds__(256) void k_ee(
    const float* __restrict__ edge_attr, const float* __restrict__ eW,
    const float* __restrict__ eB, const float* __restrict__ lin_eW,
    const float* __restrict__ att_e, const int2* __restrict__ csr_se,
    float* __restrict__ aed, int E, int N) {
    __shared__ float s_ew[256];    // [k*64+d]
    __shared__ float s_eb[64];
    __shared__ float s_wred[768];  // [l*256 + h*64 + d]
    size_t P4 = (size_t)(E + N) * 4;
    int t = threadIdx.x;
    s_ew[t] = eW[t];
    if (t < 64) s_eb[t] = eB[t];
    for (int idx = t; idx < 768; idx += 256) {
        int l = idx >> 8, hd = idx & 255, hh = hd >> 6, d = hd & 63;
        const float* We = lin_eW + (size_t)l * HD * 256;
        const float* ae = att_e + (size_t)l * 256;
        float acc = 0.f;
        for (int c = 0; c < 64; c++)
            acc = fmaf(We[d * 256 + hh * 64 + c], ae[hh * 64 + c], acc);
        s_wred[idx] = acc;
    }
    __syncthreads();
    int j0 = (blockIdx.x * 256 + t) * 4;
    if (j0 >= E) return;
    float4 a[4];
    int nv = 0;
    #pragma unroll
    for (int q = 0; q < 4; q++) {
        int j = j0 + q;
        if (j < E) {
            a[q] = *(const float4*)(edge_attr + (size_t)csr_se[j].y * 4);
            nv = q + 1;
        } else {
            a[q] = make_float4(0.f, 0.f, 0.f, 0.f);
        }
    }
    float acc[4][12];
    #pragma unroll
    for (int q = 0; q < 4; q++)
        #pragma unroll
        for (int m = 0; m < 12; m++) acc[q][m] = 0.f;
    for (int k = 0; k < HD; k++) {
        float e0 = s_ew[k], e1 = s_ew[64 + k], e2 = s_ew[128 + k], e3 = s_ew[192 + k];
        float eb = s_eb[k];
        float w[12];
        #pragma unroll
        for (int m = 0; m < 12; m++)
            w[m] = s_wred[(m >> 2) * 256 + (m & 3) * 64 + k];
        #pragma unroll
        for (int q = 0; q < 4; q++) {
            float v = fmaf(a[q].x, e0, fmaf(a[q].y, e1,
                      fmaf(a[q].z, e2, fmaf(a[q].w, e3, eb))));
            v = fmaxf(v, 0.f);
            #pragma unroll
            for (int m = 0; m < 12; m++) acc[q][m] = fmaf(v, w[m], acc[q][m]);
        }
    }
    #pragma unroll
    for (int q = 0; q < 4; q++) {
        if (q >= nv) break;
        #pragma unroll
        for (int l = 0; l < 3; l++) {
            *(float4*)(aed + l * P4 + (size_t)(j0 + q) * 4) =
                make_float4(acc[q][l * 4 + 0], acc[q][l * 4 + 1],
                            acc[q][l * 4 + 2], acc[q][l * 4 + 3]);
        }
    }
}

// ---------------- ONCE: self-loop a_ed rows by LINEARITY ----------------
__global__ void k_selfed(const int* __restrict__ row_ptr, float* __restrict__ aed,
                         int E, int N) {
    int n = blockIdx.x * blockDim.x + threadIdx.x;
    if (n >= N) return;
    size_t P4 = (size_t)(E + N) * 4;
    int r0 = row_ptr[n], r1 = row_ptr[n + 1];
    float acc[12];
    #pragma unroll
    for (int m = 0; m < 12; m++) acc[m] = 0.f;
    for (int j = r0; j < r1; j++) {
        #pragma unroll
        for (int l = 0; l < 3; l++) {
            float4 v = *(const float4*)(aed + l * P4 + (size_t)j * 4);
            acc[l * 4 + 0] += v.x; acc[l * 4 + 1] += v.y;
            acc[l * 4 + 2] += v.z; acc[l * 4 + 3] += v.w;
        }
    }
    float inv = 1.f / fmaxf((float)(r1 - r0), 1.f);
    #pragma unroll
    for (int l = 0; l < 3; l++) {
        *(float4*)(aed + l * P4 + (size_t)(E + n) * 4) =
            make_float4(acc[l * 4 + 0] * inv, acc[l * 4 + 1] * inv,
                        acc[l * 4 + 2] * inv, acc[l * 4 + 3] * inv);
    }
}

// ---------------- per-layer GAT aggregate: gather fp32 h rows (256B/edge) -----------------
// agg_h[d] += w_h * h[src][d]; z[n][h*64+d] = agg_h[d]/den_h (fp32).
// Structure frozen except z now fp32 (removes downstream bf16 converts).
__global__ __launch_bounds__(256) void k_gat(
    const float* __restrict__ h, const float* __restrict__ a_s,
    const float* __restrict__ a_d, const float* __restrict__ aedl,
    const int* __restrict__ row_ptr, const int2* __restrict__ csr_se,
    float* __restrict__ z, int N, int E) {
    int wave = threadIdx.x >> 6, lane = threadIdx.x & 63;
    int n = blockIdx.x * 4 + wave;
    if (n >= N) return;
    int g = lane >> 4, p = lane & 15;
    int r0 = row_ptr[n], r1 = row_ptr[n + 1];
    float4 ad4 = *(const float4*)(a_d + (size_t)n * 4);
    float a00 = 0.f, a01 = 0.f, a02 = 0.f, a03 = 0.f;
    float a10 = 0.f, a11 = 0.f, a12 = 0.f, a13 = 0.f;
    float a20 = 0.f, a21 = 0.f, a22 = 0.f, a23 = 0.f;
    float a30 = 0.f, a31 = 0.f, a32 = 0.f, a33 = 0.f;
    float d0 = 0.f, d1 = 0.f, d2 = 0.f, d3 = 0.f;
    if (g == 0) {
        // self loop: src = n
        float4 as4 = *(const float4*)(a_s + (size_t)n * 4);
        float4 p4 = *(const float4*)(aedl + (size_t)(E + n) * 4);
        float w0 = __expf(lrelu(as4.x + ad4.x + p4.x));
        float w1 = __expf(lrelu(as4.y + ad4.y + p4.y));
        float w2 = __expf(lrelu(as4.z + ad4.z + p4.z));
        float w3 = __expf(lrelu(as4.w + ad4.w + p4.w));
        float4 hv = *(const float4*)(h + (size_t)n * HD + p * 4);
        d0 += w0; d1 += w1; d2 += w2; d3 += w3;
        a00 = fmaf(w0, hv.x, a00); a01 = fmaf(w0, hv.y, a01);
        a02 = fmaf(w0, hv.z, a02); a03 = fmaf(w0, hv.w, a03);
        a10 = fmaf(w1, hv.x, a10); a11 = fmaf(w1, hv.y, a11);
        a12 = fmaf(w1, hv.z, a12); a13 = fmaf(w1, hv.w, a13);
        a20 = fmaf(w2, hv.x, a20); a21 = fmaf(w2, hv.y, a21);
        a22 = fmaf(w2, hv.z, a22); a23 = fmaf(w2, hv.w, a23);
        a30 = fmaf(w3, hv.x, a30); a31 = fmaf(w3, hv.y, a31);
        a32 = fmaf(w3, hv.z, a32); a33 = fmaf(w3, hv.w, a33);
    }
    int j = r0 + g;
    int2 se = (j < r1) ? csr_se[j] : make_int2(0, 0);
    for (; j < r1; j += 4) {
        int jn = j + 4;
        int2 se_n = (jn < r1) ? csr_se[jn] : make_int2(0, 0);  // prefetch
        int s = se.x;
        float4 as4 = *(const float4*)(a_s + (size_t)s * 4);
        float4 p4 = *(const float4*)(aedl + (size_t)j * 4);
        float w0 = __expf(lrelu(as4.x + ad4.x + p4.x));
        float w1 = __expf(lrelu(as4.y + ad4.y + p4.y));
        float w2 = __expf(lrelu(as4.z + ad4.z + p4.z));
        float w3 = __expf(lrelu(as4.w + ad4.w + p4.w));
        float4 hv = *(const float4*)(h + (size_t)s * HD + p * 4);
        d0 += w0; d1 += w1; d2 += w2; d3 += w3;
        a00 = fmaf(w0, hv.x, a00); a01 = fmaf(w0, hv.y, a01);
        a02 = fmaf(w0, hv.z, a02); a03 = fmaf(w0, hv.w, a03);
        a10 = fmaf(w1, hv.x, a10); a11 = fmaf(w1, hv.y, a11);
        a12 = fmaf(w1, hv.z, a12); a13 = fmaf(w1, hv.w, a13);
        a20 = fmaf(w2, hv.x, a20); a21 = fmaf(w2, hv.y, a21);
        a22 = fmaf(w2, hv.z, a22); a23 = fmaf(w2, hv.w, a23);
        a30 = fmaf(w3, hv.x, a30); a31 = fmaf(w3, hv.y, a31);
        a32 = fmaf(w3, hv.z, a32); a33 = fmaf(w3, hv.w, a33);
        se = se_n;
    }
    // reduce denominators and all 16 accumulators across the 4 lane-groups
    d0 += __shfl_xor(d0, 16); d0 += __shfl_xor(d0, 32);
    d1 += __shfl_xor(d1, 16); d1 += __shfl_xor(d1, 32);
    d2 += __shfl_xor(d2, 16); d2 += __shfl_xor(d2, 32);
    d3 += __shfl_xor(d3, 16); d3 += __shfl_xor(d3, 32);
    a00 += __shfl_xor(a00, 16); a00 += __shfl_xor(a00, 32);
    a01 += __shfl_xor(a01, 16); a01 += __shfl_xor(a01, 32);
    a02 += __shfl_xor(a02, 16); a02 += __shfl_xor(a02, 32);
    a03 += __shfl_xor(a03, 16); a03 += __shfl_xor(a03, 32);
    a10 += __shfl_xor(a10, 16); a10 += __shfl_xor(a10, 32);
    a11 += __shfl_xor(a11, 16); a11 += __shfl_xor(a11, 32);
    a12 += __shfl_xor(a12, 16); a12 += __shfl_xor(a12, 32);
    a13 += __shfl_xor(a13, 16); a13 += __shfl_xor(a13, 32);
    a20 += __shfl_xor(a20, 16); a20 += __shfl_xor(a20, 32);
    a21 += __shfl_xor(a21, 16); a21 += __shfl_xor(a21, 32);
    a22 += __shfl_xor(a22, 16); a22 += __shfl_xor(a22, 32);
    a23 += __shfl_xor(a23, 16); a23 += __shfl_xor(a23, 32);
    a30 += __shfl_xor(a30, 16); a30 += __shfl_xor(a30, 32);
    a31 += __shfl_xor(a31, 16); a31 += __shfl_xor(a31, 32);
    a32 += __shfl_xor(a32, 16); a32 += __shfl_xor(a32, 32);
    a33 += __shfl_xor(a33, 16); a33 += __shfl_xor(a33, 32);
    if (lane < 16) {
        float i0 = 1.f / d0, i1 = 1.f / d1, i2 = 1.f / d2, i3 = 1.f / d3;
        float* zr = z + (size_t)n * 256 + p * 4;
        *(float4*)(zr)       = make_float4(a00 * i0, a01 * i0, a02 * i0, a03 * i0);
        *(float4*)(zr + 64)  = make_float4(a10 * i1, a11 * i1, a12 * i1, a13 * i1);
        *(float4*)(zr + 128) = make_float4(a20 * i2, a21 * i2, a22 * i2, a23 * i2);
        *(float4*)(zr + 192) = make_float4(a30 * i3, a31 * i3, a32 * i3, a33 * i3);
    }
}

// ---------------- per-layer: h_new = relu(0.25*z@M + b) -- k_xp-template, NO LDS ---------
// M[k][c] = W[(k&63)*256 + (k>>6)*64 + c]. 256 threads = 64 channels x 4 node-groups;
// each thread owns 8 nodes (acc[8] + broadcast z loads = the envelope that never spilled).
// The LDS/K-split version spilled (VGPR 32, 480K bank conflicts, 59us).
#define PNB 32  // nodes per block = 4 groups x 8
__global__ __launch_bounds__(256) void k_post(
    const float* __restrict__ z, const float* __restrict__ W,
    const float* __restrict__ convb, float* __restrict__ h_out, int N) {
    int t = threadIdx.x;
    int c = t & 63, ng = t >> 6;
    int n0 = blockIdx.x * PNB + ng * 8;
    int nlim = N - n0;          // wave-uniform
    if (nlim <= 0) return;      // whole node-group out of range (wave-uniform exit)
    const float* zp = z + (size_t)n0 * 256;
    float acc[8];
    #pragma unroll
    for (int m = 0; m < 8; m++) acc[m] = 0.f;
    for (int k4 = 0; k4 < 256; k4 += 4) {
        int base = (k4 >> 6) * 64 + c;
        float w0 = W[((k4 & 63) + 0) * 256 + base];
        float w1 = W[((k4 & 63) + 1) * 256 + base];
        float w2 = W[((k4 & 63) + 2) * 256 + base];
        float w3 = W[((k4 & 63) + 3) * 256 + base];
        #pragma unroll
        for (int m = 0; m < 8; m++) {
            int mm = (m < nlim) ? m : 0;  // clamp for tail
            float4 zz = *(const float4*)(zp + (size_t)mm * 256 + k4);
            acc[m] = fmaf(zz.x, w0, acc[m]);
            acc[m] = fmaf(zz.y, w1, acc[m]);
            acc[m] = fmaf(zz.z, w2, acc[m]);
            acc[m] = fmaf(zz.w, w3, acc[m]);
        }
    }
    float cb = convb[c];
    #pragma unroll
    for (int m = 0; m < 8; m++) {
        int nn = n0 + m;
        if (m < nlim)
            h_out[(size_t)nn * HD + c] = fmaxf(0.25f * acc[m] + cb, 0.f);
    }
}

// ---------------- global pool: batch is SORTED -> segmented reduce ----------------
#define PCHUNK 8
__global__ void k_pool(const float* __restrict__ h, const int* __restrict__ batch,
                       float* __restrict__ pooled, int N, int B) {
    int b = blockIdx.x / PCHUNK, q = blockIdx.x % PCHUNK;
    __shared__ int sb[2];
    __shared__ float sred[256];
    int t = threadIdx.x;
    if (t == 0 || t == 64) {
        int target = b + (t ? 1 : 0);
        int lo = 0, hi = N;
        while (lo < hi) {
            int m = (lo + hi) >> 1;
            if (batch[m] < target) lo = m + 1; else hi = m;
        }
        sb[t ? 1 : 0] = lo;
    }
    __syncthreads();
    int start = sb[0], end = sb[1];
    int len = end - start;
    int c0 = start + (int)(((long long)len * q) / PCHUNK);
    int c1 = start + (int)(((long long)len * (q + 1)) / PCHUNK);
    int c = t & 63, r = t >> 6;
    float acc = 0.f;
    for (int nidx = c0 + r; nidx < c1; nidx += 4)
        acc += h[(size_t)nidx * HD + c];
    sred[t] = acc;
    __syncthreads();
    if (t < 64) {
        float v = sred[t] + sred[64 + t] + sred[128 + t] + sred[192 + t];
        if (v != 0.f) atomicAdd(&pooled[b * HD + c], v);
    }
}

// ---------------- final MLP: B blocks x 64 threads; len via binary search ----------------
__global__ void k_mlp(const float* __restrict__ u, const float* __restrict__ gW,
                      const float* __restrict__ gb, const float* __restrict__ pooled,
                      const int* __restrict__ batch, const float* __restrict__ f1W,
                      const float* __restrict__ f1b, const float* __restrict__ f2W,
                      const float* __restrict__ f2b, float* __restrict__ out,
                      int N, int B) {
    __shared__ float z[2 * HD];
    __shared__ float z1s[HD];
    __shared__ int sb[2];
    int b = blockIdx.x, t = threadIdx.x;  // 64 threads
    if (t < 2) {
        int target = b + t;
        int lo = 0, hi = N;
        while (lo < hi) {
            int m = (lo + hi) >> 1;
            if (batch[m] < target) lo = m + 1; else hi = m;
        }
        sb[t] = lo;
    }
    float acc = gb[t];
    for (int k = 0; k < 10; k++) acc = fmaf(u[b * 10 + k], gW[k * HD + t], acc);
    z[HD + t] = fmaxf(acc, 0.f);
    __syncthreads();
    float invc = 1.f / fmaxf((float)(sb[1] - sb[0]), 1.f);
    z[t] = pooled[b * HD + t] * invc;
    __syncthreads();
    float a1 = f1b[t];
    for (int k = 0; k < 2 * HD; k++) a1 = fmaf(z[k], f1W[k * HD + t], a1);
    z1s[t] = fmaxf(a1, 0.f);
    __syncthreads();
    if (t < 2) {
        float o = f2b[t];
        for (int k = 0; k < HD; k++) o = fmaf(z1s[k], f2W[k * 2 + t], o);
        out[b * 2 + t] = o;
    }
}

extern "C" void kernel_launch(void* const* d_in, const int* in_sizes, int n_in,
                              void* d_out, int out_size, void* d_ws, size_t ws_size,
                              hipStream_t stream) {
    const float* x         = (const float*)d_in[0];
    const int*   ei        = (const int*)d_in[1];
    const float* edge_attr = (const float*)d_in[2];
    const float* u         = (const float*)d_in[3];
    const int*   batch     = (const int*)d_in[4];
    const float* node_W    = (const float*)d_in[5];
    const float* node_b    = (const float*)d_in[6];
    const float* eemb_W    = (const float*)d_in[7];
    const float* eemb_b    = (const float*)d_in[8];
    const float* lin_W     = (const float*)d_in[9];
    const float* att_src   = (const float*)d_in[10];
    const float* att_dst   = (const float*)d_in[11];
    const float* lin_eW    = (const float*)d_in[12];
    const float* att_e     = (const float*)d_in[13];
    const float* conv_b    = (const float*)d_in[14];
    const float* gW        = (const float*)d_in[15];
    const float* gb        = (const float*)d_in[16];
    const float* f1W       = (const float*)d_in[17];
    const float* f1b       = (const float*)d_in[18];
    const float* f2W       = (const float*)d_in[19];
    const float* f2b       = (const float*)d_in[20];

    const int N = in_sizes[0] / 3;
    const int E = in_sizes[2] / 4;
    const int B = in_sizes[3] / 10;
    const int* src = ei;
    const int* dst = ei + E;
    const int NB = (N + 255) / 256;   // scan blocks
    const size_t P4 = (size_t)(E + N) * 4;  // aed plane stride (floats)

    // workspace carve (fp32, then ints)
    float* wsf = (float*)d_ws;
    float* h       = wsf;              wsf += (size_t)N * HD;
    float* a_s     = wsf;              wsf += (size_t)N * 4;
    float* a_d     = wsf;              wsf += (size_t)N * 4;
    float* aed     = wsf;              wsf += 3 * P4;
    float* pooled  = wsf;              wsf += (size_t)B * HD;
    float* wsd     = wsf;              wsf += 3 * 512;          // Ws/Wd tables
    float* zbuf    = wsf;              wsf += (size_t)N * 256;  // fp32 aggregate
    int* wsi = (int*)wsf;
    int2* csr_se = (int2*)wsi;         wsi += 2 * (size_t)E;    // 8B-aligned
    int* deg     = wsi;                wsi += N;
    int* row_ptr = wsi;                wsi += N + 1;
    int* cursor  = wsi;                wsi += N;
    int* tmp     = wsi;                wsi += N;
    int* bsum    = wsi;                wsi += NB + 1;

    k_init<<<(N * HD + 255) / 256, 256, 0, stream>>>(x, node_W, node_b, h,
                                                     lin_W, att_src, att_dst, wsd,
                                                     deg, cursor, pooled, N, B);
    k_deg<<<(E + 255) / 256, 256, 0, stream>>>(dst, deg, E, N);
    k_scan1<<<NB, 256, 0, stream>>>(deg, tmp, bsum, N);
    k_scan23<<<NB, 256, 0, stream>>>(tmp, bsum, row_ptr, N);
    k_csr<<<(E + 255) / 256, 256, 0, stream>>>(src, dst, row_ptr, cursor,
                                               csr_se, E, N);
    k_ee<<<(E + 1023) / 1024, 256, 0, stream>>>(edge_attr, eemb_W, eemb_b, lin_eW, att_e,
                                                csr_se, aed, E, N);
    k_selfed<<<NB, 256, 0, stream>>>(row_ptr, aed, E, N);
    k_att<<<(N * 8 + 255) / 256, 256, 0, stream>>>(h, wsd, a_s, a_d, N);
    for (int i = 0; i < 3; i++) {
        k_gat<<<(N + 3) / 4, 256, 0, stream>>>(h, a_s, a_d, aed + (size_t)i * P4,
                                               row_ptr, csr_se, zbuf, N, E);
        k_post<<<(N + PNB - 1) / PNB, 256, 0, stream>>>(zbuf,
                                                        lin_W + (size_t)i * HD * 256,
                                                        conv_b + (size_t)i * HD, h, N);
        if (i < 2)
            k_att<<<(N * 8 + 255) / 256, 256, 0, stream>>>(h, wsd + (size_t)(i + 1) * 512,
                                                           a_s, a_d, N);
    }
    k_pool<<<B * PCHUNK, 256, 0, stream>>>(h, batch, pooled, N, B);
    k_mlp<<<B, 64, 0, stream>>>(u, gW, gb, pooled, batch, f1W, f1b, f2W, f2b,
                                (float*)d_out, N, B);
}

// Round 12
// 443.161 us; speedup vs baseline: 1.0683x; 1.0683x over previous
//
#include <hip/hip_runtime.h>
#include <hip/hip_bf16.h>

#define HD 64

typedef unsigned short u16;

__device__ __forceinline__ float lrelu(float x) { return x > 0.f ? x : 0.2f * x; }
__device__ __forceinline__ int clampi(int v, int maxv) {
    return v < 0 ? 0 : (v >= maxv ? maxv - 1 : v);
}

// ---------------- init (zero deg/cursor/pooled) + node embedding + Ws/Wd precompute -------
// wsd[l][idx][d], idx = h*2+sel (sel 0=src,1=dst):
//   wsd = sum_c W_l[d][h*64+c] * att_{src|dst}[l][h][c]
// so a_s[n,h] = sum_d h[n,d]*wsd[l][h*2+0][d]  (linearity of the attention dot).
__global__ void k_init(const float* __restrict__ x, const float* __restrict__ W,
                       const float* __restrict__ b, float* __restrict__ h,
                       const float* __restrict__ lin_W, const float* __restrict__ att_src,
                       const float* __restrict__ att_dst, float* __restrict__ wsd,
                       int* deg, int* cursor, float* pooled, int N, int B) {
    int i = blockIdx.x * blockDim.x + threadIdx.x;
    if (i < N) { deg[i] = 0; cursor[i] = 0; }
    if (i < B * HD) pooled[i] = 0.f;
    if (i < 3 * 512) {
        int l = i >> 9, r = i & 511;
        int idx = r >> 6, d = r & 63;
        int hh = idx >> 1, sel = idx & 1;
        const float* att = (sel ? att_dst : att_src) + l * 256 + hh * 64;
        const float* Wrow = lin_W + (size_t)l * HD * 256 + d * 256 + hh * 64;
        float acc = 0.f;
        for (int c = 0; c < 64; c++) acc = fmaf(Wrow[c], att[c], acc);
        wsd[(l << 9) + (idx << 6) + d] = acc;
    }
    if (i < N * HD) {
        int n = i >> 6, c = i & 63;
        float acc = b[c];
        acc = fmaf(x[n * 3 + 0], W[0 * HD + c], acc);
        acc = fmaf(x[n * 3 + 1], W[1 * HD + c], acc);
        acc = fmaf(x[n * 3 + 2], W[2 * HD + c], acc);
        h[i] = fmaxf(acc, 0.f);
    }
}

// ---------------- a_s/a_d from current h (launched per layer; cheap, proven) ----------
__global__ void k_att(const float* __restrict__ h, const float* __restrict__ wsdl,
                      float* __restrict__ a_s, float* __restrict__ a_d, int N) {
    int i = blockIdx.x * blockDim.x + threadIdx.x;
    if (i >= N * 8) return;
    int n = i >> 3, idx = i & 7;
    const float* hr = h + (size_t)n * HD;
    const float* wp = wsdl + (idx << 6);
    float a = 0.f;
    for (int d = 0; d < HD; d += 4) {
        float4 hv = *(const float4*)(hr + d);
        float4 wv = *(const float4*)(wp + d);
        a = fmaf(hv.x, wv.x, a); a = fmaf(hv.y, wv.y, a);
        a = fmaf(hv.z, wv.z, a); a = fmaf(hv.w, wv.w, a);
    }
    int hd = idx >> 1, sel = idx & 1;
    if (sel) a_d[n * 4 + hd] = a;
    else     a_s[n * 4 + hd] = a;
}

// ---------------- degree histogram over dst ----------------
__global__ void k_deg(const int* __restrict__ dst, int* __restrict__ deg, int E, int N) {
    int e = blockIdx.x * blockDim.x + threadIdx.x;
    if (e < E) atomicAdd(&deg[clampi(dst[e], N)], 1);
}

// ---------------- hierarchical scan (2 kernels) ----------------
__global__ void k_scan1(const int* __restrict__ deg, int* __restrict__ tmp,
                        int* __restrict__ bsum, int N) {
    __shared__ int s[256];
    int tid = threadIdx.x;
    int i = blockIdx.x * 256 + tid;
    int v = (i < N) ? deg[i] : 0;
    s[tid] = v;
    __syncthreads();
    for (int off = 1; off < 256; off <<= 1) {
        int t = (tid >= off) ? s[tid - off] : 0;
        __syncthreads();
        s[tid] += t;
        __syncthreads();
    }
    if (i < N) tmp[i] = s[tid];
    if (tid == 255) bsum[blockIdx.x] = s[255];
}
__global__ void k_scan23(const int* __restrict__ tmp, const int* __restrict__ bsum,
                         int* __restrict__ row_ptr, int N) {
    __shared__ int s_off;
    int t = threadIdx.x;
    if (t < 64) {
        int cnt = blockIdx.x;
        int v = 0;
        for (int base = 0; base < cnt; base += 64)
            if (base + t < cnt) v += bsum[base + t];
        #pragma unroll
        for (int o = 32; o > 0; o >>= 1) v += __shfl_xor(v, o);
        if (t == 0) s_off = v;
    }
    __syncthreads();
    int i = blockIdx.x * 256 + t;
    if (i == 0) row_ptr[0] = 0;
    if (i < N) row_ptr[i + 1] = tmp[i] + s_off;
}

// ---------------- CSR scatter; packed {src, eid} int2 per slot ----------------
__global__ void k_csr(const int* __restrict__ src, const int* __restrict__ dst,
                      const int* __restrict__ row_ptr, int* __restrict__ cursor,
                      int2* __restrict__ csr_se, int E, int N) {
    int e = blockIdx.x * blockDim.x + threadIdx.x;
    if (e >= E) return;
    int d = clampi(dst[e], N);
    int pos = row_ptr[d] + atomicAdd(&cursor[d], 1);
    if (pos < E) csr_se[pos] = make_int2(clampi(src[e], N), e);
}

// ---------------- ONCE: a_ed for all 3 layers x 4 heads, CSR order ----------------
// planar output: aed[l][(E+N)][4]
__global__ __launch_bounds__(256) void k_ee(
    const float* __restrict__ edge_attr, const float* __restrict__ eW,
    const float* __restrict__ eB, const float* __restrict__ lin_eW,
    const float* __restrict__ att_e, const int2* __restrict__ csr_se,
    float* __restrict__ aed, int E, int N) {
    __shared__ float s_ew[256];    // [k*64+d]
    __shared__ float s_eb[64];
    __shared__ float s_wred[768];  // [l*256 + h*64 + d]
    size_t P4 = (size_t)(E + N) * 4;
    int t = threadIdx.x;
    s_ew[t] = eW[t];
    if (t < 64) s_eb[t] = eB[t];
    for (int idx = t; idx < 768; idx += 256) {
        int l = idx >> 8, hd = idx & 255, hh = hd >> 6, d = hd & 63;
        const float* We = lin_eW + (size_t)l * HD * 256;
        const float* ae = att_e + (size_t)l * 256;
        float acc = 0.f;
        for (int c = 0; c < 64; c++)
            acc = fmaf(We[d * 256 + hh * 64 + c], ae[hh * 64 + c], acc);
        s_wred[idx] = acc;
    }
    __syncthreads();
    int j0 = (blockIdx.x * 256 + t) * 4;
    if (j0 >= E) return;
    float4 a[4];
    int nv = 0;
    #pragma unroll
    for (int q = 0; q < 4; q++) {
        int j = j0 + q;
        if (j < E) {
            a[q] = *(const float4*)(edge_attr + (size_t)csr_se[j].y * 4);
            nv = q + 1;
        } else {
            a[q] = make_float4(0.f, 0.f, 0.f, 0.f);
        }
    }
    float acc[4][12];
    #pragma unroll
    for (int q = 0; q < 4; q++)
        #pragma unroll
        for (int m = 0; m < 12; m++) acc[q][m] = 0.f;
    for (int k = 0; k < HD; k++) {
        float e0 = s_ew[k], e1 = s_ew[64 + k], e2 = s_ew[128 + k], e3 = s_ew[192 + k];
        float eb = s_eb[k];
        float w[12];
        #pragma unroll
        for (int m = 0; m < 12; m++)
            w[m] = s_wred[(m >> 2) * 256 + (m & 3) * 64 + k];
        #pragma unroll
        for (int q = 0; q < 4; q++) {
            float v = fmaf(a[q].x, e0, fmaf(a[q].y, e1,
                      fmaf(a[q].z, e2, fmaf(a[q].w, e3, eb))));
            v = fmaxf(v, 0.f);
            #pragma unroll
            for (int m = 0; m < 12; m++) acc[q][m] = fmaf(v, w[m], acc[q][m]);
        }
    }
    #pragma unroll
    for (int q = 0; q < 4; q++) {
        if (q >= nv) break;
        #pragma unroll
        for (int l = 0; l < 3; l++) {
            *(float4*)(aed + l * P4 + (size_t)(j0 + q) * 4) =
                make_float4(acc[q][l * 4 + 0], acc[q][l * 4 + 1],
                            acc[q][l * 4 + 2], acc[q][l * 4 + 3]);
        }
    }
}

// ---------------- ONCE: self-loop a_ed rows by LINEARITY ----------------
__global__ void k_selfed(const int* __restrict__ row_ptr, float* __restrict__ aed,
                         int E, int N) {
    int n = blockIdx.x * blockDim.x + threadIdx.x;
    if (n >= N) return;
    size_t P4 = (size_t)(E + N) * 4;
    int r0 = row_ptr[n], r1 = row_ptr[n + 1];
    float acc[12];
    #pragma unroll
    for (int m = 0; m < 12; m++) acc[m] = 0.f;
    for (int j = r0; j < r1; j++) {
        #pragma unroll
        for (int l = 0; l < 3; l++) {
            float4 v = *(const float4*)(aed + l * P4 + (size_t)j * 4);
            acc[l * 4 + 0] += v.x; acc[l * 4 + 1] += v.y;
            acc[l * 4 + 2] += v.z; acc[l * 4 + 3] += v.w;
        }
    }
    float inv = 1.f / fmaxf((float)(r1 - r0), 1.f);
    #pragma unroll
    for (int l = 0; l < 3; l++) {
        *(float4*)(aed + l * P4 + (size_t)(E + n) * 4) =
            make_float4(acc[l * 4 + 0] * inv, acc[l * 4 + 1] * inv,
                        acc[l * 4 + 2] * inv, acc[l * 4 + 3] * inv);
    }
}

// ---------------- per-layer GAT aggregate: gather fp32 h rows (256B/edge) -----------------
// agg_h[d] += w_h * h[src][d]; z[n][h*64+d] = agg_h[d]/den_h (fp32). Structure frozen.
__global__ __launch_bounds__(256) void k_gat(
    const float* __restrict__ h, const float* __restrict__ a_s,
    const float* __restrict__ a_d, const float* __restrict__ aedl,
    const int* __restrict__ row_ptr, const int2* __restrict__ csr_se,
    float* __restrict__ z, int N, int E) {
    int wave = threadIdx.x >> 6, lane = threadIdx.x & 63;
    int n = blockIdx.x * 4 + wave;
    if (n >= N) return;
    int g = lane >> 4, p = lane & 15;
    int r0 = row_ptr[n], r1 = row_ptr[n + 1];
    float4 ad4 = *(const float4*)(a_d + (size_t)n * 4);
    float a00 = 0.f, a01 = 0.f, a02 = 0.f, a03 = 0.f;
    float a10 = 0.f, a11 = 0.f, a12 = 0.f, a13 = 0.f;
    float a20 = 0.f, a21 = 0.f, a22 = 0.f, a23 = 0.f;
    float a30 = 0.f, a31 = 0.f, a32 = 0.f, a33 = 0.f;
    float d0 = 0.f, d1 = 0.f, d2 = 0.f, d3 = 0.f;
    if (g == 0) {
        // self loop: src = n
        float4 as4 = *(const float4*)(a_s + (size_t)n * 4);
        float4 p4 = *(const float4*)(aedl + (size_t)(E + n) * 4);
        float w0 = __expf(lrelu(as4.x + ad4.x + p4.x));
        float w1 = __expf(lrelu(as4.y + ad4.y + p4.y));
        float w2 = __expf(lrelu(as4.z + ad4.z + p4.z));
        float w3 = __expf(lrelu(as4.w + ad4.w + p4.w));
        float4 hv = *(const float4*)(h + (size_t)n * HD + p * 4);
        d0 += w0; d1 += w1; d2 += w2; d3 += w3;
        a00 = fmaf(w0, hv.x, a00); a01 = fmaf(w0, hv.y, a01);
        a02 = fmaf(w0, hv.z, a02); a03 = fmaf(w0, hv.w, a03);
        a10 = fmaf(w1, hv.x, a10); a11 = fmaf(w1, hv.y, a11);
        a12 = fmaf(w1, hv.z, a12); a13 = fmaf(w1, hv.w, a13);
        a20 = fmaf(w2, hv.x, a20); a21 = fmaf(w2, hv.y, a21);
        a22 = fmaf(w2, hv.z, a22); a23 = fmaf(w2, hv.w, a23);
        a30 = fmaf(w3, hv.x, a30); a31 = fmaf(w3, hv.y, a31);
        a32 = fmaf(w3, hv.z, a32); a33 = fmaf(w3, hv.w, a33);
    }
    int j = r0 + g;
    int2 se = (j < r1) ? csr_se[j] : make_int2(0, 0);
    for (; j < r1; j += 4) {
        int jn = j + 4;
        int2 se_n = (jn < r1) ? csr_se[jn] : make_int2(0, 0);  // prefetch
        int s = se.x;
        float4 as4 = *(const float4*)(a_s + (size_t)s * 4);
        float4 p4 = *(const float4*)(aedl + (size_t)j * 4);
        float w0 = __expf(lrelu(as4.x + ad4.x + p4.x));
        float w1 = __expf(lrelu(as4.y + ad4.y + p4.y));
        float w2 = __expf(lrelu(as4.z + ad4.z + p4.z));
        float w3 = __expf(lrelu(as4.w + ad4.w + p4.w));
        float4 hv = *(const float4*)(h + (size_t)s * HD + p * 4);
        d0 += w0; d1 += w1; d2 += w2; d3 += w3;
        a00 = fmaf(w0, hv.x, a00); a01 = fmaf(w0, hv.y, a01);
        a02 = fmaf(w0, hv.z, a02); a03 = fmaf(w0, hv.w, a03);
        a10 = fmaf(w1, hv.x, a10); a11 = fmaf(w1, hv.y, a11);
        a12 = fmaf(w1, hv.z, a12); a13 = fmaf(w1, hv.w, a13);
        a20 = fmaf(w2, hv.x, a20); a21 = fmaf(w2, hv.y, a21);
        a22 = fmaf(w2, hv.z, a22); a23 = fmaf(w2, hv.w, a23);
        a30 = fmaf(w3, hv.x, a30); a31 = fmaf(w3, hv.y, a31);
        a32 = fmaf(w3, hv.z, a32); a33 = fmaf(w3, hv.w, a33);
        se = se_n;
    }
    // reduce denominators and all 16 accumulators across the 4 lane-groups
    d0 += __shfl_xor(d0, 16); d0 += __shfl_xor(d0, 32);
    d1 += __shfl_xor(d1, 16); d1 += __shfl_xor(d1, 32);
    d2 += __shfl_xor(d2, 16); d2 += __shfl_xor(d2, 32);
    d3 += __shfl_xor(d3, 16); d3 += __shfl_xor(d3, 32);
    a00 += __shfl_xor(a00, 16); a00 += __shfl_xor(a00, 32);
    a01 += __shfl_xor(a01, 16); a01 += __shfl_xor(a01, 32);
    a02 += __shfl_xor(a02, 16); a02 += __shfl_xor(a02, 32);
    a03 += __shfl_xor(a03, 16); a03 += __shfl_xor(a03, 32);
    a10 += __shfl_xor(a10, 16); a10 += __shfl_xor(a10, 32);
    a11 += __shfl_xor(a11, 16); a11 += __shfl_xor(a11, 32);
    a12 += __shfl_xor(a12, 16); a12 += __shfl_xor(a12, 32);
    a13 += __shfl_xor(a13, 16); a13 += __shfl_xor(a13, 32);
    a20 += __shfl_xor(a20, 16); a20 += __shfl_xor(a20, 32);
    a21 += __shfl_xor(a21, 16); a21 += __shfl_xor(a21, 32);
    a22 += __shfl_xor(a22, 16); a22 += __shfl_xor(a22, 32);
    a23 += __shfl_xor(a23, 16); a23 += __shfl_xor(a23, 32);
    a30 += __shfl_xor(a30, 16); a30 += __shfl_xor(a30, 32);
    a31 += __shfl_xor(a31, 16); a31 += __shfl_xor(a31, 32);
    a32 += __shfl_xor(a32, 16); a32 += __shfl_xor(a32, 32);
    a33 += __shfl_xor(a33, 16); a33 += __shfl_xor(a33, 32);
    if (lane < 16) {
        float i0 = 1.f / d0, i1 = 1.f / d1, i2 = 1.f / d2, i3 = 1.f / d3;
        float* zr = z + (size_t)n * 256 + p * 4;
        *(float4*)(zr)       = make_float4(a00 * i0, a01 * i0, a02 * i0, a03 * i0);
        *(float4*)(zr + 64)  = make_float4(a10 * i1, a11 * i1, a12 * i1, a13 * i1);
        *(float4*)(zr + 128) = make_float4(a20 * i2, a21 * i2, a22 * i2, a23 * i2);
        *(float4*)(zr + 192) = make_float4(a30 * i3, a31 * i3, a32 * i3, a33 * i3);
    }
}

// ---------------- per-layer: h_new = relu(0.25*z@M + b) -- NO LDS, 4 nodes/thread --------
// r11's 8-node version was latency-starved: 625 blocks = 2.4 waves/SIMD, VALUBusy 18%.
// 4 nodes/thread doubles the grid (1250 blocks, ~4.9 waves/SIMD) at half the serial work.
#define PNB 16  // nodes per block = 4 groups x 4
__global__ __launch_bounds__(256) void k_post(
    const float* __restrict__ z, const float* __restrict__ W,
    const float* __restrict__ convb, float* __restrict__ h_out, int N) {
    int t = threadIdx.x;
    int c = t & 63, ng = t >> 6;
    int n0 = blockIdx.x * PNB + ng * 4;
    int nlim = N - n0;          // wave-uniform
    if (nlim <= 0) return;      // whole node-group out of range (wave-uniform exit)
    const float* zp = z + (size_t)n0 * 256;
    float acc[4];
    #pragma unroll
    for (int m = 0; m < 4; m++) acc[m] = 0.f;
    for (int k4 = 0; k4 < 256; k4 += 4) {
        int base = (k4 >> 6) * 64 + c;
        float w0 = W[((k4 & 63) + 0) * 256 + base];
        float w1 = W[((k4 & 63) + 1) * 256 + base];
        float w2 = W[((k4 & 63) + 2) * 256 + base];
        float w3 = W[((k4 & 63) + 3) * 256 + base];
        #pragma unroll
        for (int m = 0; m < 4; m++) {
            int mm = (m < nlim) ? m : 0;  // clamp for tail
            float4 zz = *(const float4*)(zp + (size_t)mm * 256 + k4);
            acc[m] = fmaf(zz.x, w0, acc[m]);
            acc[m] = fmaf(zz.y, w1, acc[m]);
            acc[m] = fmaf(zz.z, w2, acc[m]);
            acc[m] = fmaf(zz.w, w3, acc[m]);
        }
    }
    float cb = convb[c];
    #pragma unroll
    for (int m = 0; m < 4; m++) {
        int nn = n0 + m;
        if (m < nlim)
            h_out[(size_t)nn * HD + c] = fmaxf(0.25f * acc[m] + cb, 0.f);
    }
}

// ---------------- global pool: batch is SORTED -> segmented reduce ----------------
#define PCHUNK 8
__global__ void k_pool(const float* __restrict__ h, const int* __restrict__ batch,
                       float* __restrict__ pooled, int N, int B) {
    int b = blockIdx.x / PCHUNK, q = blockIdx.x % PCHUNK;
    __shared__ int sb[2];
    __shared__ float sred[256];
    int t = threadIdx.x;
    if (t == 0 || t == 64) {
        int target = b + (t ? 1 : 0);
        int lo = 0, hi = N;
        while (lo < hi) {
            int m = (lo + hi) >> 1;
            if (batch[m] < target) lo = m + 1; else hi = m;
        }
        sb[t ? 1 : 0] = lo;
    }
    __syncthreads();
    int start = sb[0], end = sb[1];
    int len = end - start;
    int c0 = start + (int)(((long long)len * q) / PCHUNK);
    int c1 = start + (int)(((long long)len * (q + 1)) / PCHUNK);
    int c = t & 63, r = t >> 6;
    float acc = 0.f;
    for (int nidx = c0 + r; nidx < c1; nidx += 4)
        acc += h[(size_t)nidx * HD + c];
    sred[t] = acc;
    __syncthreads();
    if (t < 64) {
        float v = sred[t] + sred[64 + t] + sred[128 + t] + sred[192 + t];
        if (v != 0.f) atomicAdd(&pooled[b * HD + c], v);
    }
}

// ---------------- final MLP: B blocks x 64 threads; len via binary search ----------------
__global__ void k_mlp(const float* __restrict__ u, const float* __restrict__ gW,
                      const float* __restrict__ gb, const float* __restrict__ pooled,
                      const int* __restrict__ batch, const float* __restrict__ f1W,
                      const float* __restrict__ f1b, const float* __restrict__ f2W,
                      const float* __restrict__ f2b, float* __restrict__ out,
                      int N, int B) {
    __shared__ float z[2 * HD];
    __shared__ float z1s[HD];
    __shared__ int sb[2];
    int b = blockIdx.x, t = threadIdx.x;  // 64 threads
    if (t < 2) {
        int target = b + t;
        int lo = 0, hi = N;
        while (lo < hi) {
            int m = (lo + hi) >> 1;
            if (batch[m] < target) lo = m + 1; else hi = m;
        }
        sb[t] = lo;
    }
    float acc = gb[t];
    for (int k = 0; k < 10; k++) acc = fmaf(u[b * 10 + k], gW[k * HD + t], acc);
    z[HD + t] = fmaxf(acc, 0.f);
    __syncthreads();
    float invc = 1.f / fmaxf((float)(sb[1] - sb[0]), 1.f);
    z[t] = pooled[b * HD + t] * invc;
    __syncthreads();
    float a1 = f1b[t];
    for (int k = 0; k < 2 * HD; k++) a1 = fmaf(z[k], f1W[k * HD + t], a1);
    z1s[t] = fmaxf(a1, 0.f);
    __syncthreads();
    if (t < 2) {
        float o = f2b[t];
        for (int k = 0; k < HD; k++) o = fmaf(z1s[k], f2W[k * 2 + t], o);
        out[b * 2 + t] = o;
    }
}

extern "C" void kernel_launch(void* const* d_in, const int* in_sizes, int n_in,
                              void* d_out, int out_size, void* d_ws, size_t ws_size,
                              hipStream_t stream) {
    const float* x         = (const float*)d_in[0];
    const int*   ei        = (const int*)d_in[1];
    const float* edge_attr = (const float*)d_in[2];
    const float* u         = (const float*)d_in[3];
    const int*   batch     = (const int*)d_in[4];
    const float* node_W    = (const float*)d_in[5];
    const float* node_b    = (const float*)d_in[6];
    const float* eemb_W    = (const float*)d_in[7];
    const float* eemb_b    = (const float*)d_in[8];
    const float* lin_W     = (const float*)d_in[9];
    const float* att_src   = (const float*)d_in[10];
    const float* att_dst   = (const float*)d_in[11];
    const float* lin_eW    = (const float*)d_in[12];
    const float* att_e     = (const float*)d_in[13];
    const float* conv_b    = (const float*)d_in[14];
    const float* gW        = (const float*)d_in[15];
    const float* gb        = (const float*)d_in[16];
    const float* f1W       = (const float*)d_in[17];
    const float* f1b       = (const float*)d_in[18];
    const float* f2W       = (const float*)d_in[19];
    const float* f2b       = (const float*)d_in[20];

    const int N = in_sizes[0] / 3;
    const int E = in_sizes[2] / 4;
    const int B = in_sizes[3] / 10;
    const int* src = ei;
    const int* dst = ei + E;
    const int NB = (N + 255) / 256;   // scan blocks
    const size_t P4 = (size_t)(E + N) * 4;  // aed plane stride (floats)

    // workspace carve (fp32, then ints)
    float* wsf = (float*)d_ws;
    float* h       = wsf;              wsf += (size_t)N * HD;
    float* a_s     = wsf;              wsf += (size_t)N * 4;
    float* a_d     = wsf;              wsf += (size_t)N * 4;
    float* aed     = wsf;              wsf += 3 * P4;
    float* pooled  = wsf;              wsf += (size_t)B * HD;
    float* wsd     = wsf;              wsf += 3 * 512;          // Ws/Wd tables
    float* zbuf    = wsf;              wsf += (size_t)N * 256;  // fp32 aggregate
    int* wsi = (int*)wsf;
    int2* csr_se = (int2*)wsi;         wsi += 2 * (size_t)E;    // 8B-aligned
    int* deg     = wsi;                wsi += N;
    int* row_ptr = wsi;                wsi += N + 1;
    int* cursor  = wsi;                wsi += N;
    int* tmp     = wsi;                wsi += N;
    int* bsum    = wsi;                wsi += NB + 1;

    k_init<<<(N * HD + 255) / 256, 256, 0, stream>>>(x, node_W, node_b, h,
                                                     lin_W, att_src, att_dst, wsd,
                                                     deg, cursor, pooled, N, B);
    k_deg<<<(E + 255) / 256, 256, 0, stream>>>(dst, deg, E, N);
    k_scan1<<<NB, 256, 0, stream>>>(deg, tmp, bsum, N);
    k_scan23<<<NB, 256, 0, stream>>>(tmp, bsum, row_ptr, N);
    k_csr<<<(E + 255) / 256, 256, 0, stream>>>(src, dst, row_ptr, cursor,
                                               csr_se, E, N);
    k_ee<<<(E + 1023) / 1024, 256, 0, stream>>>(edge_attr, eemb_W, eemb_b, lin_eW, att_e,
                                                csr_se, aed, E, N);
    k_selfed<<<NB, 256, 0, stream>>>(row_ptr, aed, E, N);
    k_att<<<(N * 8 + 255) / 256, 256, 0, stream>>>(h, wsd, a_s, a_d, N);
    for (int i = 0; i < 3; i++) {
        k_gat<<<(N + 3) / 4, 256, 0, stream>>>(h, a_s, a_d, aed + (size_t)i * P4,
                                               row_ptr, csr_se, zbuf, N, E);
        k_post<<<(N + PNB - 1) / PNB, 256, 0, stream>>>(zbuf,
                                                        lin_W + (size_t)i * HD * 256,
                                                        conv_b + (size_t)i * HD, h, N);
        if (i < 2)
            k_att<<<(N * 8 + 255) / 256, 256, 0, stream>>>(h, wsd + (size_t)(i + 1) * 512,
                                                           a_s, a_d, N);
    }
    k_pool<<<B * PCHUNK, 256, 0, stream>>>(h, batch, pooled, N, B);
    k_mlp<<<B, 64, 0, stream>>>(u, gW, gb, pooled, batch, f1W, f1b, f2W, f2b,
                                (float*)d_out, N, B);
}

// Round 14
// 365.252 us; speedup vs baseline: 1.2961x; 1.2133x over previous
//
#include <hip/hip_runtime.h>
#include <hip/hip_bf16.h>

#define HD 64

typedef unsigned short u16;

__device__ __forceinline__ float lrelu(float x) { return x > 0.f ? x : 0.2f * x; }
__device__ __forceinline__ int clampi(int v, int maxv) {
    return v < 0 ? 0 : (v >= maxv ? maxv - 1 : v);
}

// ---------------- init (zero deg/cursor/pooled) + node embedding + Ws/Wd precompute -------
// wsd[l][idx][d], idx = h*2+sel (sel 0=src,1=dst):
//   wsd = sum_c W_l[d][h*64+c] * att_{src|dst}[l][h][c]
// so a_s[n,h] = sum_d h[n,d]*wsd[l][h*2+0][d]  (linearity of the attention dot).
__global__ void k_init(const float* __restrict__ x, const float* __restrict__ W,
                       const float* __restrict__ b, float* __restrict__ h,
                       const float* __restrict__ lin_W, const float* __restrict__ att_src,
                       const float* __restrict__ att_dst, float* __restrict__ wsd,
                       int* deg, int* cursor, float* pooled, int N, int B) {
    int i = blockIdx.x * blockDim.x + threadIdx.x;
    if (i < N) { deg[i] = 0; cursor[i] = 0; }
    if (i < B * HD) pooled[i] = 0.f;
    if (i < 3 * 512) {
        int l = i >> 9, r = i & 511;
        int idx = r >> 6, d = r & 63;
        int hh = idx >> 1, sel = idx & 1;
        const float* att = (sel ? att_dst : att_src) + l * 256 + hh * 64;
        const float* Wrow = lin_W + (size_t)l * HD * 256 + d * 256 + hh * 64;
        float acc = 0.f;
        for (int c = 0; c < 64; c++) acc = fmaf(Wrow[c], att[c], acc);
        wsd[(l << 9) + (idx << 6) + d] = acc;
    }
    if (i < N * HD) {
        int n = i >> 6, c = i & 63;
        float acc = b[c];
        acc = fmaf(x[n * 3 + 0], W[0 * HD + c], acc);
        acc = fmaf(x[n * 3 + 1], W[1 * HD + c], acc);
        acc = fmaf(x[n * 3 + 2], W[2 * HD + c], acc);
        h[i] = fmaxf(acc, 0.f);
    }
}

// ---------------- a_s/a_d from current h (launched per layer; cheap, proven) ----------
__global__ void k_att(const float* __restrict__ h, const float* __restrict__ wsdl,
                      float* __restrict__ a_s, float* __restrict__ a_d, int N) {
    int i = blockIdx.x * blockDim.x + threadIdx.x;
    if (i >= N * 8) return;
    int n = i >> 3, idx = i & 7;
    const float* hr = h + (size_t)n * HD;
    const float* wp = wsdl + (idx << 6);
    float a = 0.f;
    for (int d = 0; d < HD; d += 4) {
        float4 hv = *(const float4*)(hr + d);
        float4 wv = *(const float4*)(wp + d);
        a = fmaf(hv.x, wv.x, a); a = fmaf(hv.y, wv.y, a);
        a = fmaf(hv.z, wv.z, a); a = fmaf(hv.w, wv.w, a);
    }
    int hd = idx >> 1, sel = idx & 1;
    if (sel) a_d[n * 4 + hd] = a;
    else     a_s[n * 4 + hd] = a;
}

// ---------------- degree histogram over dst ----------------
__global__ void k_deg(const int* __restrict__ dst, int* __restrict__ deg, int E, int N) {
    int e = blockIdx.x * blockDim.x + threadIdx.x;
    if (e < E) atomicAdd(&deg[clampi(dst[e], N)], 1);
}

// ---------------- hierarchical scan (2 kernels) ----------------
__global__ void k_scan1(const int* __restrict__ deg, int* __restrict__ tmp,
                        int* __restrict__ bsum, int N) {
    __shared__ int s[256];
    int tid = threadIdx.x;
    int i = blockIdx.x * 256 + tid;
    int v = (i < N) ? deg[i] : 0;
    s[tid] = v;
    __syncthreads();
    for (int off = 1; off < 256; off <<= 1) {
        int t = (tid >= off) ? s[tid - off] : 0;
        __syncthreads();
        s[tid] += t;
        __syncthreads();
    }
    if (i < N) tmp[i] = s[tid];
    if (tid == 255) bsum[blockIdx.x] = s[255];
}
__global__ void k_scan23(const int* __restrict__ tmp, const int* __restrict__ bsum,
                         int* __restrict__ row_ptr, int N) {
    __shared__ int s_off;
    int t = threadIdx.x;
    if (t < 64) {
        int cnt = blockIdx.x;
        int v = 0;
        for (int base = 0; base < cnt; base += 64)
            if (base + t < cnt) v += bsum[base + t];
        #pragma unroll
        for (int o = 32; o > 0; o >>= 1) v += __shfl_xor(v, o);
        if (t == 0) s_off = v;
    }
    __syncthreads();
    int i = blockIdx.x * 256 + t;
    if (i == 0) row_ptr[0] = 0;
    if (i < N) row_ptr[i + 1] = tmp[i] + s_off;
}

// ---------------- CSR scatter; packed {src, eid} int2 per slot ----------------
__global__ void k_csr(const int* __restrict__ src, const int* __restrict__ dst,
                      const int* __restrict__ row_ptr, int* __restrict__ cursor,
                      int2* __restrict__ csr_se, int E, int N) {
    int e = blockIdx.x * blockDim.x + threadIdx.x;
    if (e >= E) return;
    int d = clampi(dst[e], N);
    int pos = row_ptr[d] + atomicAdd(&cursor[d], 1);
    if (pos < E) csr_se[pos] = make_int2(clampi(src[e], N), e);
}

// ---------------- ONCE: a_ed for all 3 layers x 4 heads, CSR order ----------------
// planar output: aed[l][(E+N)][4]
__global__ __launch_bounds__(256) void k_ee(
    const float* __restrict__ edge_attr, const float* __restrict__ eW,
    const float* __restrict__ eB, const float* __restrict__ lin_eW,
    const float* __restrict__ att_e, const int2* __restrict__ csr_se,
    float* __restrict__ aed, int E, int N) {
    __shared__ float s_ew[256];    // [k*64+d]
    __shared__ float s_eb[64];
    __shared__ float s_wred[768];  // [l*256 + h*64 + d]
    size_t P4 = (size_t)(E + N) * 4;
    int t = threadIdx.x;
    s_ew[t] = eW[t];
    if (t < 64) s_eb[t] = eB[t];
    for (int idx = t; idx < 768; idx += 256) {
        int l = idx >> 8, hd = idx & 255, hh = hd >> 6, d = hd & 63;
        const float* We = lin_eW + (size_t)l * HD * 256;
        const float* ae = att_e + (size_t)l * 256;
        float acc = 0.f;
        for (int c = 0; c < 64; c++)
            acc = fmaf(We[d * 256 + hh * 64 + c], ae[hh * 64 + c], acc);
        s_wred[idx] = acc;
    }
    __syncthreads();
    int j0 = (blockIdx.x * 256 + t) * 4;
    if (j0 >= E) return;
    float4 a[4];
    int nv = 0;
    #pragma unroll
    for (int q = 0; q < 4; q++) {
        int j = j0 + q;
        if (j < E) {
            a[q] = *(const float4*)(edge_attr + (size_t)csr_se[j].y * 4);
            nv = q + 1;
        } else {
            a[q] = make_float4(0.f, 0.f, 0.f, 0.f);
        }
    }
    float acc[4][12];
    #pragma unroll
    for (int q = 0; q < 4; q++)
        #pragma unroll
        for (int m = 0; m < 12; m++) acc[q][m] = 0.f;
    for (int k = 0; k < HD; k++) {
        float e0 = s_ew[k], e1 = s_ew[64 + k], e2 = s_ew[128 + k], e3 = s_ew[192 + k];
        float eb = s_eb[k];
        float w[12];
        #pragma unroll
        for (int m = 0; m < 12; m++)
            w[m] = s_wred[(m >> 2) * 256 + (m & 3) * 64 + k];
        #pragma unroll
        for (int q = 0; q < 4; q++) {
            float v = fmaf(a[q].x, e0, fmaf(a[q].y, e1,
                      fmaf(a[q].z, e2, fmaf(a[q].w, e3, eb))));
            v = fmaxf(v, 0.f);
            #pragma unroll
            for (int m = 0; m < 12; m++) acc[q][m] = fmaf(v, w[m], acc[q][m]);
        }
    }
    #pragma unroll
    for (int q = 0; q < 4; q++) {
        if (q >= nv) break;
        #pragma unroll
        for (int l = 0; l < 3; l++) {
            *(float4*)(aed + l * P4 + (size_t)(j0 + q) * 4) =
                make_float4(acc[q][l * 4 + 0], acc[q][l * 4 + 1],
                            acc[q][l * 4 + 2], acc[q][l * 4 + 3]);
        }
    }
}

// ---------------- ONCE: self-loop a_ed rows by LINEARITY ----------------
__global__ void k_selfed(const int* __restrict__ row_ptr, float* __restrict__ aed,
                         int E, int N) {
    int n = blockIdx.x * blockDim.x + threadIdx.x;
    if (n >= N) return;
    size_t P4 = (size_t)(E + N) * 4;
    int r0 = row_ptr[n], r1 = row_ptr[n + 1];
    float acc[12];
    #pragma unroll
    for (int m = 0; m < 12; m++) acc[m] = 0.f;
    for (int j = r0; j < r1; j++) {
        #pragma unroll
        for (int l = 0; l < 3; l++) {
            float4 v = *(const float4*)(aed + l * P4 + (size_t)j * 4);
            acc[l * 4 + 0] += v.x; acc[l * 4 + 1] += v.y;
            acc[l * 4 + 2] += v.z; acc[l * 4 + 3] += v.w;
        }
    }
    float inv = 1.f / fmaxf((float)(r1 - r0), 1.f);
    #pragma unroll
    for (int l = 0; l < 3; l++) {
        *(float4*)(aed + l * P4 + (size_t)(E + n) * 4) =
            make_float4(acc[l * 4 + 0] * inv, acc[l * 4 + 1] * inv,
                        acc[l * 4 + 2] * inv, acc[l * 4 + 3] * inv);
    }
}

// ---------------- per-layer GAT aggregate: gather fp32 h rows (256B/edge) -----------------
// agg_h[d] += w_h * h[src][d]; z[n][h*64+d] = agg_h[d]/den_h (fp32). Structure frozen.
__global__ __launch_bounds__(256) void k_gat(
    const float* __restrict__ h, const float* __restrict__ a_s,
    const float* __restrict__ a_d, const float* __restrict__ aedl,
    const int* __restrict__ row_ptr, const int2* __restrict__ csr_se,
    float* __restrict__ z, int N, int E) {
    int wave = threadIdx.x >> 6, lane = threadIdx.x & 63;
    int n = blockIdx.x * 4 + wave;
    if (n >= N) return;
    int g = lane >> 4, p = lane & 15;
    int r0 = row_ptr[n], r1 = row_ptr[n + 1];
    float4 ad4 = *(const float4*)(a_d + (size_t)n * 4);
    float a00 = 0.f, a01 = 0.f, a02 = 0.f, a03 = 0.f;
    float a10 = 0.f, a11 = 0.f, a12 = 0.f, a13 = 0.f;
    float a20 = 0.f, a21 = 0.f, a22 = 0.f, a23 = 0.f;
    float a30 = 0.f, a31 = 0.f, a32 = 0.f, a33 = 0.f;
    float d0 = 0.f, d1 = 0.f, d2 = 0.f, d3 = 0.f;
    if (g == 0) {
        // self loop: src = n
        float4 as4 = *(const float4*)(a_s + (size_t)n * 4);
        float4 p4 = *(const float4*)(aedl + (size_t)(E + n) * 4);
        float w0 = __expf(lrelu(as4.x + ad4.x + p4.x));
        float w1 = __expf(lrelu(as4.y + ad4.y + p4.y));
        float w2 = __expf(lrelu(as4.z + ad4.z + p4.z));
        float w3 = __expf(lrelu(as4.w + ad4.w + p4.w));
        float4 hv = *(const float4*)(h + (size_t)n * HD + p * 4);
        d0 += w0; d1 += w1; d2 += w2; d3 += w3;
        a00 = fmaf(w0, hv.x, a00); a01 = fmaf(w0, hv.y, a01);
        a02 = fmaf(w0, hv.z, a02); a03 = fmaf(w0, hv.w, a03);
        a10 = fmaf(w1, hv.x, a10); a11 = fmaf(w1, hv.y, a11);
        a12 = fmaf(w1, hv.z, a12); a13 = fmaf(w1, hv.w, a13);
        a20 = fmaf(w2, hv.x, a20); a21 = fmaf(w2, hv.y, a21);
        a22 = fmaf(w2, hv.z, a22); a23 = fmaf(w2, hv.w, a23);
        a30 = fmaf(w3, hv.x, a30); a31 = fmaf(w3, hv.y, a31);
        a32 = fmaf(w3, hv.z, a32); a33 = fmaf(w3, hv.w, a33);
    }
    int j = r0 + g;
    int2 se = (j < r1) ? csr_se[j] : make_int2(0, 0);
    for (; j < r1; j += 4) {
        int jn = j + 4;
        int2 se_n = (jn < r1) ? csr_se[jn] : make_int2(0, 0);  // prefetch
        int s = se.x;
        float4 as4 = *(const float4*)(a_s + (size_t)s * 4);
        float4 p4 = *(const float4*)(aedl + (size_t)j * 4);
        float w0 = __expf(lrelu(as4.x + ad4.x + p4.x));
        float w1 = __expf(lrelu(as4.y + ad4.y + p4.y));
        float w2 = __expf(lrelu(as4.z + ad4.z + p4.z));
        float w3 = __expf(lrelu(as4.w + ad4.w + p4.w));
        float4 hv = *(const float4*)(h + (size_t)s * HD + p * 4);
        d0 += w0; d1 += w1; d2 += w2; d3 += w3;
        a00 = fmaf(w0, hv.x, a00); a01 = fmaf(w0, hv.y, a01);
        a02 = fmaf(w0, hv.z, a02); a03 = fmaf(w0, hv.w, a03);
        a10 = fmaf(w1, hv.x, a10); a11 = fmaf(w1, hv.y, a11);
        a12 = fmaf(w1, hv.z, a12); a13 = fmaf(w1, hv.w, a13);
        a20 = fmaf(w2, hv.x, a20); a21 = fmaf(w2, hv.y, a21);
        a22 = fmaf(w2, hv.z, a22); a23 = fmaf(w2, hv.w, a23);
        a30 = fmaf(w3, hv.x, a30); a31 = fmaf(w3, hv.y, a31);
        a32 = fmaf(w3, hv.z, a32); a33 = fmaf(w3, hv.w, a33);
        se = se_n;
    }
    // reduce denominators and all 16 accumulators across the 4 lane-groups
    d0 += __shfl_xor(d0, 16); d0 += __shfl_xor(d0, 32);
    d1 += __shfl_xor(d1, 16); d1 += __shfl_xor(d1, 32);
    d2 += __shfl_xor(d2, 16); d2 += __shfl_xor(d2, 32);
    d3 += __shfl_xor(d3, 16); d3 += __shfl_xor(d3, 32);
    a00 += __shfl_xor(a00, 16); a00 += __shfl_xor(a00, 32);
    a01 += __shfl_xor(a01, 16); a01 += __shfl_xor(a01, 32);
    a02 += __shfl_xor(a02, 16); a02 += __shfl_xor(a02, 32);
    a03 += __shfl_xor(a03, 16); a03 += __shfl_xor(a03, 32);
    a10 += __shfl_xor(a10, 16); a10 += __shfl_xor(a10, 32);
    a11 += __shfl_xor(a11, 16); a11 += __shfl_xor(a11, 32);
    a12 += __shfl_xor(a12, 16); a12 += __shfl_xor(a12, 32);
    a13 += __shfl_xor(a13, 16); a13 += __shfl_xor(a13, 32);
    a20 += __shfl_xor(a20, 16); a20 += __shfl_xor(a20, 32);
    a21 += __shfl_xor(a21, 16); a21 += __shfl_xor(a21, 32);
    a22 += __shfl_xor(a22, 16); a22 += __shfl_xor(a22, 32);
    a23 += __shfl_xor(a23, 16); a23 += __shfl_xor(a23, 32);
    a30 += __shfl_xor(a30, 16); a30 += __shfl_xor(a30, 32);
    a31 += __shfl_xor(a31, 16); a31 += __shfl_xor(a31, 32);
    a32 += __shfl_xor(a32, 16); a32 += __shfl_xor(a32, 32);
    a33 += __shfl_xor(a33, 16); a33 += __shfl_xor(a33, 32);
    if (lane < 16) {
        float i0 = 1.f / d0, i1 = 1.f / d1, i2 = 1.f / d2, i3 = 1.f / d3;
        float* zr = z + (size_t)n * 256 + p * 4;
        *(float4*)(zr)       = make_float4(a00 * i0, a01 * i0, a02 * i0, a03 * i0);
        *(float4*)(zr + 64)  = make_float4(a10 * i1, a11 * i1, a12 * i1, a13 * i1);
        *(float4*)(zr + 128) = make_float4(a20 * i2, a21 * i2, a22 * i2, a23 * i2);
        *(float4*)(zr + 192) = make_float4(a30 * i3, a31 * i3, a32 * i3, a33 * i3);
    }
}

// ---------------- per-layer: h_new = relu(0.25*z@M + b) -- LDS-staged z, coalesced -------
// r12's no-LDS version was 16B-per-instruction broadcast-load latency-bound (52us,
// VALUBusy 22%). Here: stage 16 nodes' z rows (16KB LDS) with coalesced float4 loads
// (1024B/instr), compute with wave-uniform LDS broadcast reads (conflict-free).
// Register envelope ~35 VGPR (acc[4]); no K-split, no fused epilogue (r10's spill trap).
#define PNB 16  // nodes per block = 4 groups x 4
__global__ __launch_bounds__(256) void k_post(
    const float* __restrict__ z, const float* __restrict__ W,
    const float* __restrict__ convb, float* __restrict__ h_out, int N) {
    __shared__ float zs[PNB * 256];  // 16 KB
    int t = threadIdx.x;
    int n0 = blockIdx.x * PNB;
    int navail = N - n0; if (navail > PNB) navail = PNB;  // >= 1
    const float* zp = z + (size_t)n0 * 256;
    int nfloat = navail * 256;
    #pragma unroll
    for (int it = 0; it < 16; it++) {
        int idx = it * 1024 + t * 4;
        if (idx < nfloat)
            *(float4*)&zs[idx] = *(const float4*)(zp + idx);
    }
    __syncthreads();
    int c = t & 63, ng = t >> 6;
    float acc[4];
    #pragma unroll
    for (int m = 0; m < 4; m++) acc[m] = 0.f;
    for (int k4 = 0; k4 < 256; k4 += 4) {
        int base = (k4 >> 6) * 64 + c;
        float w0 = W[((k4 & 63) + 0) * 256 + base];
        float w1 = W[((k4 & 63) + 1) * 256 + base];
        float w2 = W[((k4 & 63) + 2) * 256 + base];
        float w3 = W[((k4 & 63) + 3) * 256 + base];
        #pragma unroll
        for (int m = 0; m < 4; m++) {
            int ln = ng * 4 + m;
            int lnc = (ln < navail) ? ln : 0;  // clamp (wave-uniform)
            float4 zz = *(const float4*)&zs[lnc * 256 + k4];
            acc[m] = fmaf(zz.x, w0, acc[m]);
            acc[m] = fmaf(zz.y, w1, acc[m]);
            acc[m] = fmaf(zz.z, w2, acc[m]);
            acc[m] = fmaf(zz.w, w3, acc[m]);
        }
    }
    float cb = convb[c];
    #pragma unroll
    for (int m = 0; m < 4; m++) {
        int ln = ng * 4 + m;
        if (ln < navail)
            h_out[(size_t)(n0 + ln) * HD + c] = fmaxf(0.25f * acc[m] + cb, 0.f);
    }
}

// ---------------- global pool: batch is SORTED -> segmented reduce ----------------
#define PCHUNK 8
__global__ void k_pool(const float* __restrict__ h, const int* __restrict__ batch,
                       float* __restrict__ pooled, int N, int B) {
    int b = blockIdx.x / PCHUNK, q = blockIdx.x % PCHUNK;
    __shared__ int sb[2];
    __shared__ float sred[256];
    int t = threadIdx.x;
    if (t == 0 || t == 64) {
        int target = b + (t ? 1 : 0);
        int lo = 0, hi = N;
        while (lo < hi) {
            int m = (lo + hi) >> 1;
            if (batch[m] < target) lo = m + 1; else hi = m;
        }
        sb[t ? 1 : 0] = lo;
    }
    __syncthreads();
    int start = sb[0], end = sb[1];
    int len = end - start;
    int c0 = start + (int)(((long long)len * q) / PCHUNK);
    int c1 = start + (int)(((long long)len * (q + 1)) / PCHUNK);
    int c = t & 63, r = t >> 6;
    float acc = 0.f;
    for (int nidx = c0 + r; nidx < c1; nidx += 4)
        acc += h[(size_t)nidx * HD + c];
    sred[t] = acc;
    __syncthreads();
    if (t < 64) {
        float v = sred[t] + sred[64 + t] + sred[128 + t] + sred[192 + t];
        if (v != 0.f) atomicAdd(&pooled[b * HD + c], v);
    }
}

// ---------------- final MLP: B blocks x 64 threads; len via binary search ----------------
__global__ void k_mlp(const float* __restrict__ u, const float* __restrict__ gW,
                      const float* __restrict__ gb, const float* __restrict__ pooled,
                      const int* __restrict__ batch, const float* __restrict__ f1W,
                      const float* __restrict__ f1b, const float* __restrict__ f2W,
                      const float* __restrict__ f2b, float* __restrict__ out,
                      int N, int B) {
    __shared__ float z[2 * HD];
    __shared__ float z1s[HD];
    __shared__ int sb[2];
    int b = blockIdx.x, t = threadIdx.x;  // 64 threads
    if (t < 2) {
        int target = b + t;
        int lo = 0, hi = N;
        while (lo < hi) {
            int m = (lo + hi) >> 1;
            if (batch[m] < target) lo = m + 1; else hi = m;
        }
        sb[t] = lo;
    }
    float acc = gb[t];
    for (int k = 0; k < 10; k++) acc = fmaf(u[b * 10 + k], gW[k * HD + t], acc);
    z[HD + t] = fmaxf(acc, 0.f);
    __syncthreads();
    float invc = 1.f / fmaxf((float)(sb[1] - sb[0]), 1.f);
    z[t] = pooled[b * HD + t] * invc;
    __syncthreads();
    float a1 = f1b[t];
    for (int k = 0; k < 2 * HD; k++) a1 = fmaf(z[k], f1W[k * HD + t], a1);
    z1s[t] = fmaxf(a1, 0.f);
    __syncthreads();
    if (t < 2) {
        float o = f2b[t];
        for (int k = 0; k < HD; k++) o = fmaf(z1s[k], f2W[k * 2 + t], o);
        out[b * 2 + t] = o;
    }
}

extern "C" void kernel_launch(void* const* d_in, const int* in_sizes, int n_in,
                              void* d_out, int out_size, void* d_ws, size_t ws_size,
                              hipStream_t stream) {
    const float* x         = (const float*)d_in[0];
    const int*   ei        = (const int*)d_in[1];
    const float* edge_attr = (const float*)d_in[2];
    const float* u         = (const float*)d_in[3];
    const int*   batch     = (const int*)d_in[4];
    const float* node_W    = (const float*)d_in[5];
    const float* node_b    = (const float*)d_in[6];
    const float* eemb_W    = (const float*)d_in[7];
    const float* eemb_b    = (const float*)d_in[8];
    const float* lin_W     = (const float*)d_in[9];
    const float* att_src   = (const float*)d_in[10];
    const float* att_dst   = (const float*)d_in[11];
    const float* lin_eW    = (const float*)d_in[12];
    const float* att_e     = (const float*)d_in[13];
    const float* conv_b    = (const float*)d_in[14];
    const float* gW        = (const float*)d_in[15];
    const float* gb        = (const float*)d_in[16];
    const float* f1W       = (const float*)d_in[17];
    const float* f1b       = (const float*)d_in[18];
    const float* f2W       = (const float*)d_in[19];
    const float* f2b       = (const float*)d_in[20];

    const int N = in_sizes[0] / 3;
    const int E = in_sizes[2] / 4;
    const int B = in_sizes[3] / 10;
    const int* src = ei;
    const int* dst = ei + E;
    const int NB = (N + 255) / 256;   // scan blocks
    const size_t P4 = (size_t)(E + N) * 4;  // aed plane stride (floats)

    // workspace carve (fp32, then ints)
    float* wsf = (float*)d_ws;
    float* h       = wsf;              wsf += (size_t)N * HD;
    float* a_s     = wsf;              wsf += (size_t)N * 4;
    float* a_d     = wsf;              wsf += (size_t)N * 4;
    float* aed     = wsf;              wsf += 3 * P4;
    float* pooled  = wsf;              wsf += (size_t)B * HD;
    float* wsd     = wsf;              wsf += 3 * 512;          // Ws/Wd tables
    float* zbuf    = wsf;              wsf += (size_t)N * 256;  // fp32 aggregate
    int* wsi = (int*)wsf;
    int2* csr_se = (int2*)wsi;         wsi += 2 * (size_t)E;    // 8B-aligned
    int* deg     = wsi;                wsi += N;
    int* row_ptr = wsi;                wsi += N + 1;
    int* cursor  = wsi;                wsi += N;
    int* tmp     = wsi;                wsi += N;
    int* bsum    = wsi;                wsi += NB + 1;

    k_init<<<(N * HD + 255) / 256, 256, 0, stream>>>(x, node_W, node_b, h,
                                                     lin_W, att_src, att_dst, wsd,
                                                     deg, cursor, pooled, N, B);
    k_deg<<<(E + 255) / 256, 256, 0, stream>>>(dst, deg, E, N);
    k_scan1<<<NB, 256, 0, stream>>>(deg, tmp, bsum, N);
    k_scan23<<<NB, 256, 0, stream>>>(tmp, bsum, row_ptr, N);
    k_csr<<<(E + 255) / 256, 256, 0, stream>>>(src, dst, row_ptr, cursor,
                                               csr_se, E, N);
    k_ee<<<(E + 1023) / 1024, 256, 0, stream>>>(edge_attr, eemb_W, eemb_b, lin_eW, att_e,
                                                csr_se, aed, E, N);
    k_selfed<<<NB, 256, 0, stream>>>(row_ptr, aed, E, N);
    k_att<<<(N * 8 + 255) / 256, 256, 0, stream>>>(h, wsd, a_s, a_d, N);
    for (int i = 0; i < 3; i++) {
        k_gat<<<(N + 3) / 4, 256, 0, stream>>>(h, a_s, a_d, aed + (size_t)i * P4,
                                               row_ptr, csr_se, zbuf, N, E);
        k_post<<<(N + PNB - 1) / PNB, 256, 0, stream>>>(zbuf,
                                                        lin_W + (size_t)i * HD * 256,
                                                        conv_b + (size_t)i * HD, h, N);
        if (i < 2)
            k_att<<<(N * 8 + 255) / 256, 256, 0, stream>>>(h, wsd + (size_t)(i + 1) * 512,
                                                           a_s, a_d, N);
    }
    k_pool<<<B * PCHUNK, 256, 0, stream>>>(h, batch, pooled, N, B);
    k_mlp<<<B, 64, 0, stream>>>(u, gW, gb, pooled, batch, f1W, f1b, f2W, f2b,
                                (float*)d_out, N, B);
}